// Round 1
// baseline (698.137 us; speedup 1.0000x reference)
//
#include <hip/hip_runtime.h>

#define T       2048
#define FEAT    1024
#define BTOT    64
#define BHALF   32
#define KSEL    20
#define NROWS   (BTOT * T)          // 131072 rows
#define MAG_BLOCKS 1280             // 5 blocks/CU (32 KB LDS each) x 256 CU
#define MAG_WAVES  (MAG_BLOCKS * 4) // 5120 persistent waves

// ---------------------------------------------------------------------------
// Kernel A v3: per-(b,t) magnitude, numpy-pairwise-exact, persistent waves.
//
// One wave per row, ~26 rows per wave. No __syncthreads (LDS slices are
// wave-private). Staging uses global_load_lds width=16 (direct HBM->LDS,
// no VGPR round trip), double-buffered: row r+1's 4 loads are issued before
// computing row r, with a counted s_waitcnt vmcnt(4) so the memory queue
// never drains in steady state.
//
// global_load_lds writes linearly (wave-uniform base + lane*16), so the old
// "+4 pad per 128 floats" is impossible. Instead a bijective XOR swizzle is
// applied on the GLOBAL source address (linear LDS dest + same swizzle on the
// LDS read side): physical float p holds logical element e = p ^ ((B&3)<<3),
// B = e>>7. Chain reads (lane(B,j), elem 128B + j + 8i) then land on banks
// j + 8*((i&3)^(B&3)) -> 4 banks x 2-way per i = conflict-free on gfx950.
// Summation order is bit-identical to the verified v2 kernel:
//   per j: sequential sum of 16 stride-8 squares; xor-butterfly 1,2,4 = leaf
//   tree, 8,16,32 = top tree.
// ---------------------------------------------------------------------------
__global__ __launch_bounds__(256) void mag_kernel(
        const float* __restrict__ feat,
        float* __restrict__ keys)
{
#pragma clang fp contract(off)
    const int wid  = threadIdx.x >> 6;
    const int lane = threadIdx.x & 63;
    const int gw   = blockIdx.x * 4 + wid;   // persistent wave id, 0..5119

    __shared__ float sh[4 * 2048];           // 2 x 1024-float buffers per wave
    float* buf = sh + wid * 2048;

    const int B    = lane >> 3;
    const int j    = lane & 7;
    const int base = B * 128 + j;
    const int bl8  = lane & 24;              // 8*(B&3): XOR term for swizzle

    // stage one row: 4 x global_load_lds dwordx4 (1 KB each), linear LDS dest,
    // swizzled global source. float4-group q in LDS holds global float4-group
    // q ^ (((q>>5)&3)<<1)  (bits 5-6 of q = B&3, bits 1-2 of q = float bits 3-4).
    auto stage = [&](int row, float* dst) {
        const float4* src4 = (const float4*)(feat + (size_t)row * FEAT);
#pragma unroll
        for (int it = 0; it < 4; ++it) {
            int q  = it * 64 + lane;                 // physical float4 group
            int qg = q ^ (((q >> 5) & 3) << 1);      // swizzled global group
            __builtin_amdgcn_global_load_lds(
                (const __attribute__((address_space(1))) void*)(src4 + qg),
                (__attribute__((address_space(3))) void*)(dst + it * 256),
                16, 0, 0);
        }
    };

    int r = gw;
    if (r < NROWS) stage(r, buf);
    int cur = 0;
    while (r < NROWS) {
        const int rn = r + MAG_WAVES;
        if (rn < NROWS) {
            stage(rn, buf + ((cur ^ 1) << 10));
            // keep next row's 4 loads in flight; wait only for current row's 4
            asm volatile("s_waitcnt vmcnt(4)" ::: "memory");
        } else {
            asm volatile("s_waitcnt vmcnt(0)" ::: "memory");
        }

        const float* lds = buf + (cur << 10);

        // numpy-exact chain: element i lives at base + (8*i ^ bl8)
        float w0  = lds[base + bl8];                 // i = 0
        float acc = w0 * w0;
#pragma unroll
        for (int i = 1; i < 16; ++i) {
            float w = lds[base + ((8 * i) ^ bl8)];
            float p = w * w;
            acc = acc + p;
        }
        // leaf tree then top tree (fp add commutative -> butterfly bit-exact)
        acc = acc + __shfl_xor(acc, 1);
        acc = acc + __shfl_xor(acc, 2);
        acc = acc + __shfl_xor(acc, 4);
        acc = acc + __shfl_xor(acc, 8);
        acc = acc + __shfl_xor(acc, 16);
        acc = acc + __shfl_xor(acc, 32);

        if (lane == 0) keys[r] = sqrtf(acc);         // raw magnitude (mask in topk)

        // ensure all ds_reads of buf[cur] retired before next iter's stage
        // overwrites this buffer
        asm volatile("s_waitcnt lgkmcnt(0)" ::: "memory");
        cur ^= 1;
        r = rn;
    }
}

// ---------------------------------------------------------------------------
// Kernel B v3: dropout mask applied here (removes the dependent mask load --
// and its pipeline-draining vmcnt(0) -- from the streaming mag kernel), then
// per-batch-row top-20 exactly as the verified v2: candidates in 8 packed u64
// registers, one barrier per round, numpy n=20 pairwise mean.
// ---------------------------------------------------------------------------
__global__ __launch_bounds__(256) void topk_kernel(
        const float* __restrict__ keys,
        const float* __restrict__ scores,
        const float* __restrict__ mask_abn,
        const float* __restrict__ mask_nor,
        int* __restrict__ sel_idx,
        float* __restrict__ out)
{
#pragma clang fp contract(off)
    const int b    = blockIdx.x;           // 0..63
    const int tid  = threadIdx.x;
    const int lane = tid & 63;
    const int wid  = tid >> 6;

    __shared__ unsigned long long wmax[2][4];

    // candidate i = tid + 256*s ; pack (key_bits<<32) | (~idx)
    unsigned long long p[8];
#pragma unroll
    for (int s = 0; s < 8; ++s) {
        int i = tid + 256 * s;
        float v = keys[b * T + i];
        float m = (b < BHALF) ? mask_nor[b * T + i]
                              : mask_abn[(b - BHALF) * T + i];
        float key = (m > 0.1f) ? (v * (1.0f / 0.9f)) : 0.0f;
        p[s] = ((unsigned long long)__float_as_uint(key) << 32) |
               (unsigned long long)(0xFFFFFFFFu - (unsigned)i);
        // keys are >= 0, so u32 float compare == float compare
    }

    int sel_local[KSEL];

    for (int k = 0; k < KSEL; ++k) {
        unsigned long long best = 0ull;
#pragma unroll
        for (int s = 0; s < 8; ++s)
            if (p[s] > best) best = p[s];
#pragma unroll
        for (int d = 1; d < 64; d <<= 1) {
            unsigned long long o = __shfl_xor(best, d);
            if (o > best) best = o;
        }
        if (lane == 0) wmax[k & 1][wid] = best;
        __syncthreads();
        unsigned long long g = wmax[k & 1][0];
#pragma unroll
        for (int w = 1; w < 4; ++w)
            if (wmax[k & 1][w] > g) g = wmax[k & 1][w];
        int idx = (int)(0xFFFFFFFFu - (unsigned)(g & 0xFFFFFFFFull));
        sel_local[k] = idx;
        // owner clears its candidate
        if ((idx & 255) == tid) p[idx >> 8] = 0ull;
    }

    if (tid == 0) {
        // numpy pairwise sum, n=20
        float a[KSEL];
        for (int k = 0; k < KSEL; ++k) a[k] = scores[b * T + sel_local[k]];
        float r[8];
        for (int jj = 0; jj < 8; ++jj) r[jj] = a[jj];
        for (int jj = 0; jj < 8; ++jj) r[jj] = r[jj] + a[8 + jj];
        float res = ((r[0] + r[1]) + (r[2] + r[3])) + ((r[4] + r[5]) + (r[6] + r[7]));
        res = res + a[16];
        res = res + a[17];
        res = res + a[18];
        res = res + a[19];
        float mean = res / 20.0f;
        int o = (b >= BHALF) ? (b - BHALF) : (BHALF + b);
        out[o] = mean;
    }
    if (tid < KSEL) sel_idx[b * KSEL + tid] = sel_local[tid];
}

// ---------------------------------------------------------------------------
// Kernel C: gather selected feature rows (exact fp32 copies). Unchanged.
// ---------------------------------------------------------------------------
__global__ __launch_bounds__(256) void gather_kernel(
        const float* __restrict__ feat,
        const int* __restrict__ sel_idx,
        float* __restrict__ out)
{
    const int k = blockIdx.x;   // 0..19
    const int b = blockIdx.y;   // 0..63
    const int t = sel_idx[b * KSEL + k];
    const float4* __restrict__ src =
        (const float4*)(feat + ((size_t)b * T + (size_t)t) * FEAT);
    size_t off;
    if (b >= BHALF) {   // abnormal block first in output
        off = 64 + ((size_t)(b - BHALF) * KSEL + k) * FEAT;
    } else {
        off = 64 + (size_t)BHALF * KSEL * FEAT + ((size_t)b * KSEL + k) * FEAT;
    }
    float4* __restrict__ dst = (float4*)(out + off);
    dst[threadIdx.x] = src[threadIdx.x];
}

extern "C" void kernel_launch(void* const* d_in, const int* in_sizes, int n_in,
                              void* d_out, int out_size, void* d_ws, size_t ws_size,
                              hipStream_t stream)
{
    const float* feat   = (const float*)d_in[0];   // (64,2048,1024)
    const float* scores = (const float*)d_in[1];   // (64,2048,1)
    const float* mabn   = (const float*)d_in[2];   // (32,2048)
    const float* mnor   = (const float*)d_in[3];   // (32,2048)
    float* out = (float*)d_out;

    float* keys = (float*)d_ws;                            // 64*2048 floats (raw mags)
    int*   sel  = (int*)((char*)d_ws + (size_t)BTOT * T * sizeof(float));

    mag_kernel<<<MAG_BLOCKS, 256, 0, stream>>>(feat, keys);
    topk_kernel<<<BTOT, 256, 0, stream>>>(keys, scores, mabn, mnor, sel, out);
    gather_kernel<<<dim3(KSEL, BTOT), 256, 0, stream>>>(feat, sel, out);
}